// Round 11
// baseline (595.307 us; speedup 1.0000x reference)
//
#include <hip/hip_runtime.h>

#define N_NODES 100000
#define N_EDGES 3200000
#define FEAT 64
#define NUM_RELS 16
#define CAP 48
#define OVF_CAP 32768
#define FILL_RANGES 16
#define NODES_PER_R 6250        // N_NODES / FILL_RANGES exact
#define FILL_CHUNKS 128
#define EDGES_PER_CHUNK 25000   // N_EDGES / FILL_CHUNKS exact
#define FILL_BLOCKS (FILL_RANGES * FILL_CHUNKS)   // 2048
#define NODE_TILES 1563         // ceil(N_NODES / 64)
#define NGEMM (NODE_TILES * 4)  // gemm blocks (4 rel-groups)

typedef float f32x4 __attribute__((ext_vector_type(4)));
typedef float f32x16 __attribute__((ext_vector_type(16)));
typedef short s16x8 __attribute__((ext_vector_type(8)));
typedef int   i32x2 __attribute__((ext_vector_type(2)));
typedef int   i32x4 __attribute__((ext_vector_type(4)));

__device__ __forceinline__ unsigned short f32_to_bf16_rne(float x) {
    unsigned int u = __float_as_uint(x);
    unsigned int r = (u + 0x7fffu + ((u >> 16) & 1u)) >> 16;
    return (unsigned short)r;
}
__device__ __forceinline__ float bf16_to_f32(unsigned short s) {
    return __uint_as_float(((unsigned int)s) << 16);
}
// T offset (in shorts) for (node s, rel r): blocked layout [N/16][R][16][64]
__device__ __forceinline__ int t_offset(int s, int r) {
    return ((s >> 4) << 14) | (r << 10) | ((s & 15) << 6);
}

// Wt[r][o][k] = bf16(W[r][k][o])
__global__ __launch_bounds__(256) void cvt_w_kernel(const float* __restrict__ W,
                                                    unsigned short* __restrict__ Wt)
{
    int t = blockIdx.x * 256 + threadIdx.x;          // 16*64*64 threads
    int r = t >> 12, o = (t >> 6) & 63, k = t & 63;
    Wt[t] = f32_to_bf16_rne(W[(r << 12) + (k << 6) + o]);
}

// ---- fused: gemm (rel-split) + single-pass bucketed fill --------------------
// Blocks [0,NGEMM): gemm for node tile (bid>>2), rel group (bid&3); h is read
// as f32 and converted in-register (no hb staging buffer / cvt_h pass).
// Blocks [NGEMM,+FILL_BLOCKS): fill role, block=(range,chunk): range=b&15
// keeps each XCD's live pay window ~2.4-4.8 MB (round-8's thrash control),
// chunk=b>>4 scans 25K sequential edges. One pass over the edge list total.
__global__ __launch_bounds__(256) void gemm_fill_kernel(
    const float* __restrict__ h,             // [N][64] f32
    const unsigned short* __restrict__ Wt,   // [16][o][k] bf16
    unsigned short* __restrict__ T,          // [N/16][16][16][64] bf16
    const int* __restrict__ src, const int* __restrict__ dst,
    const int* __restrict__ rel, const float* __restrict__ norm,
    int* __restrict__ cnt, int* __restrict__ ovfc, i32x4* __restrict__ ovf,
    i32x2* __restrict__ pay)
{
    if ((int)blockIdx.x >= NGEMM) {
        // ---- fill role ----
        const int b     = blockIdx.x - NGEMM;
        const int range = b & (FILL_RANGES - 1);
        const int chunk = b >> 4;
        const int lo = range * NODES_PER_R, hi = lo + NODES_PER_R;
        const int e0 = chunk * EDGES_PER_CHUNK;
        const int e1 = e0 + EDGES_PER_CHUNK;
        for (int e = e0 + threadIdx.x; e < e1; e += 256) {
            int d = __builtin_nontemporal_load(&dst[e]);
            if (d >= lo && d < hi) {
                int s   = __builtin_nontemporal_load(&src[e]);
                int rl  = __builtin_nontemporal_load(&rel[e]);
                float nv = __builtin_nontemporal_load(&norm[e]);
                int tofs = t_offset(s, rl);
                int pos = atomicAdd(&cnt[d], 1);
                if (pos < CAP) {
                    i32x2 p; p.x = tofs; p.y = __float_as_int(nv);
                    pay[(size_t)d * CAP + pos] = p;
                } else {
                    int op = atomicAdd(ovfc, 1);
                    if (op < OVF_CAP) {
                        i32x4 o; o.x = d; o.y = tofs;
                        o.z = __float_as_int(nv); o.w = 0;
                        ovf[op] = o;
                    }
                }
            }
        }
        return;
    }

    // ---- gemm role ----
    __shared__ short lds[4][16][68];                 // per-wave 16x64 tile, stride 68
    const int lane  = threadIdx.x & 63;
    const int w     = threadIdx.x >> 6;
    const int tile  = blockIdx.x >> 2;
    const int rg    = blockIdx.x & 3;                // rels rg*4..rg*4+3
    const int row0  = tile * 64 + w * 16;
    if (row0 >= N_NODES) return;                     // N%16==0: full tiles only
    const int q     = lane & 15;
    const int g4    = lane >> 4;

    // load h row f32, convert to bf16 fragments in-register
    const float* ap = h + ((size_t)(row0 + q) << 6) + (g4 << 3);
    f32x4 v0 = *reinterpret_cast<const f32x4*>(ap);
    f32x4 v1 = *reinterpret_cast<const f32x4*>(ap + 4);
    f32x4 v2 = *reinterpret_cast<const f32x4*>(ap + 32);
    f32x4 v3 = *reinterpret_cast<const f32x4*>(ap + 36);
    s16x8 a0, a1;
    #pragma unroll
    for (int j = 0; j < 4; ++j) {
        a0[j]     = (short)f32_to_bf16_rne(v0[j]);
        a0[4 + j] = (short)f32_to_bf16_rne(v1[j]);
        a1[j]     = (short)f32_to_bf16_rne(v2[j]);
        a1[4 + j] = (short)f32_to_bf16_rne(v3[j]);
    }

    const unsigned short* wbase = Wt + ((size_t)q << 6) + (g4 << 3);
    unsigned short* tb = T + ((size_t)(row0 >> 4) << 14);
    const int nrd = lane >> 4;
    const int c   = lane & 15;

    auto loadB = [&](s16x8* Bf, int r) {
        const unsigned short* wp = wbase + ((size_t)r << 12);
        #pragma unroll
        for (int t = 0; t < 4; ++t)
            #pragma unroll
            for (int kh = 0; kh < 2; ++kh)
                Bf[t * 2 + kh] = *reinterpret_cast<const s16x8*>(wp + (t << 10) + (kh << 5));
    };
    auto compStore = [&](const s16x8* Bf, int rr) {
        f32x4 acc[4] = {f32x4{0,0,0,0}, f32x4{0,0,0,0}, f32x4{0,0,0,0}, f32x4{0,0,0,0}};
        #pragma unroll
        for (int t = 0; t < 4; ++t) {
            acc[t] = __builtin_amdgcn_mfma_f32_16x16x32_bf16(Bf[t*2+0], a0, acc[t], 0, 0, 0);
            acc[t] = __builtin_amdgcn_mfma_f32_16x16x32_bf16(Bf[t*2+1], a1, acc[t], 0, 0, 0);
        }
        #pragma unroll
        for (int t = 0; t < 4; ++t) {
            i32x2 pk;
            pk.x = (int)((unsigned)f32_to_bf16_rne(acc[t][0]) |
                         ((unsigned)f32_to_bf16_rne(acc[t][1]) << 16));
            pk.y = (int)((unsigned)f32_to_bf16_rne(acc[t][2]) |
                         ((unsigned)f32_to_bf16_rne(acc[t][3]) << 16));
            *reinterpret_cast<i32x2*>(&lds[w][q][g4 * 4 + t * 16]) = pk;
        }
        asm volatile("s_waitcnt lgkmcnt(0)" ::: "memory");   // per-wave LDS drain
        unsigned short* tr = tb + (rr << 10);
        #pragma unroll
        for (int j = 0; j < 4; ++j) {
            const int n = nrd + 4 * j;
            i32x2 v = *reinterpret_cast<const i32x2*>(&lds[w][n][c * 4]);
            *reinterpret_cast<i32x2*>(tr + (n << 6) + (c << 2)) = v;
        }
    };

    const int r0 = rg * 4;
    s16x8 B0[8], B1[8];
    loadB(B0, r0);
    loadB(B1, r0 + 1);
    compStore(B0, r0);
    loadB(B0, r0 + 2);
    compStore(B1, r0 + 1);
    loadB(B1, r0 + 3);
    compStore(B0, r0 + 2);
    compStore(B1, r0 + 3);
}

// ---------------- aggregate: all nodes, one launch ---------------------------
__global__ __launch_bounds__(256) void agg_kernel(
    const unsigned short* __restrict__ T,    // blocked layout
    const i32x2* __restrict__ pay,           // [N][CAP] {t_offset, norm}
    const int* __restrict__ cnt,             // [N]
    const int* __restrict__ ovfc, const i32x4* __restrict__ ovf,
    float* __restrict__ out)                 // [N][64]
{
    const int lane = threadIdx.x & 63;
    const int d    = blockIdx.x * 4 + (threadIdx.x >> 6);   // grid covers N exactly

    const int degRaw = __builtin_amdgcn_readfirstlane(cnt[d]);
    const int deg    = min(degRaw, CAP);
    const i32x2* pp  = pay + (size_t)d * CAP;

    float acc = 0.f;
    int i = 0;
    for (; i + 4 <= deg; i += 4) {
        i32x2 p0 = __builtin_nontemporal_load(&pp[i]);
        i32x2 p1 = __builtin_nontemporal_load(&pp[i + 1]);
        i32x2 p2 = __builtin_nontemporal_load(&pp[i + 2]);
        i32x2 p3 = __builtin_nontemporal_load(&pp[i + 3]);
        const unsigned short t0 = T[(size_t)(unsigned)p0.x + lane];
        const unsigned short t1 = T[(size_t)(unsigned)p1.x + lane];
        const unsigned short t2 = T[(size_t)(unsigned)p2.x + lane];
        const unsigned short t3 = T[(size_t)(unsigned)p3.x + lane];
        acc = fmaf(__int_as_float(p0.y), bf16_to_f32(t0), acc);
        acc = fmaf(__int_as_float(p1.y), bf16_to_f32(t1), acc);
        acc = fmaf(__int_as_float(p2.y), bf16_to_f32(t2), acc);
        acc = fmaf(__int_as_float(p3.y), bf16_to_f32(t3), acc);
    }
    for (; i < deg; ++i) {
        i32x2 p = __builtin_nontemporal_load(&pp[i]);
        const unsigned short t = T[(size_t)(unsigned)p.x + lane];
        acc = fmaf(__int_as_float(p.y), bf16_to_f32(t), acc);
    }
    if (degRaw > CAP) {                      // exact overflow handling (rare, ~0.2%)
        const int no = min(__builtin_amdgcn_readfirstlane(*ovfc), OVF_CAP);
        for (int j = 0; j < no; ++j) {
            i32x4 o = ovf[j];
            if (o.x == d) {
                const unsigned short t = T[(size_t)(unsigned)o.y + lane];
                acc = fmaf(__int_as_float(o.z), bf16_to_f32(t), acc);
            }
        }
    }
    out[((size_t)d << 6) + lane] = fmaxf(acc, 0.f);
}

// ---------------- atomic fallback (no workspace) ----------------
__global__ __launch_bounds__(256) void rgcn_edge_kernel(
    const float* __restrict__ h, const float* __restrict__ W,
    const float* __restrict__ norm, const int* __restrict__ src,
    const int* __restrict__ dst, const int* __restrict__ rel,
    float* __restrict__ out)
{
    const int lane = threadIdx.x & 63;
    const int w    = threadIdx.x >> 6;
    const int r    = blockIdx.x & 15;
    const int inst = blockIdx.x >> 4;
    const int wavesPerRel = (gridDim.x >> 4) * 4;
    const int wi   = inst * 4 + w;

    float wreg[64];
    const float* Wr = W + (size_t)r * (FEAT * FEAT) + lane;
    #pragma unroll
    for (int d = 0; d < 64; ++d) wreg[d] = Wr[d * 64];

    const int nChunks = N_EDGES / 64;
    for (int c = wi; c < nChunks; c += wavesPerRel) {
        const int base = c * 64;
        unsigned long long m = __ballot(rel[base + lane] == r);
        while (m) {
            const int idx = __ffsll(m) - 1;
            m &= (m - 1);
            const int e = base + idx;
            const int se = __builtin_amdgcn_readfirstlane(src[e]);
            const int de = __builtin_amdgcn_readfirstlane(dst[e]);
            const float nv = __uint_as_float(
                __builtin_amdgcn_readfirstlane(__float_as_uint(norm[e])));
            const float* hp = h + ((size_t)se << 6);
            f32x16 ha, hb2, hc, hd;
            asm volatile(
                "s_load_dwordx16 %0, %4, 0x0\n\ts_load_dwordx16 %1, %4, 0x40\n\t"
                "s_load_dwordx16 %2, %4, 0x80\n\ts_load_dwordx16 %3, %4, 0xc0\n\t"
                "s_waitcnt lgkmcnt(0)"
                : "=&s"(ha), "=&s"(hb2), "=&s"(hc), "=&s"(hd) : "s"(hp));
            float a0 = 0.f, a1 = 0.f, a2 = 0.f, a3 = 0.f;
            #pragma unroll
            for (int j = 0; j < 16; ++j) {
                a0 = fmaf(ha[j], wreg[j], a0);       a1 = fmaf(hb2[j], wreg[16 + j], a1);
                a2 = fmaf(hc[j], wreg[32 + j], a2);  a3 = fmaf(hd[j], wreg[48 + j], a3);
            }
            unsafeAtomicAdd(&out[(size_t)de * FEAT + lane], ((a0 + a1) + (a2 + a3)) * nv);
        }
    }
}

__global__ __launch_bounds__(256) void relu_kernel(float4* __restrict__ out, int n4)
{
    int i = blockIdx.x * 256 + threadIdx.x;
    if (i < n4) {
        float4 v = out[i];
        v.x = fmaxf(v.x, 0.f); v.y = fmaxf(v.y, 0.f);
        v.z = fmaxf(v.z, 0.f); v.w = fmaxf(v.w, 0.f);
        out[i] = v;
    }
}

// ---------------- host ----------------
static inline size_t align256(size_t x) { return (x + 255) & ~(size_t)255; }

extern "C" void kernel_launch(void* const* d_in, const int* in_sizes, int n_in,
                              void* d_out, int out_size, void* d_ws, size_t ws_size,
                              hipStream_t stream)
{
    (void)in_sizes; (void)n_in;

    const float* h    = (const float*)d_in[0];
    const float* W    = (const float*)d_in[1];
    const float* norm = (const float*)d_in[2];
    const int*   src  = (const int*)d_in[3];
    const int*   dst  = (const int*)d_in[4];
    const int*   rel  = (const int*)d_in[5];
    float*       out  = (float*)d_out;

    const size_t szT    = (size_t)N_NODES * NUM_RELS * FEAT * 2;   // 204.8 MB
    const size_t szWt   = (size_t)NUM_RELS * FEAT * FEAT * 2;      // 128 KB
    const size_t szCnt  = (size_t)N_NODES * 4;                     // 400 KB
    const size_t szPay  = (size_t)N_NODES * CAP * 8;               // 38.4 MB
    const size_t szOvf  = (size_t)OVF_CAP * 16;                    // 512 KB

    const size_t need = align256(szT) + align256(szWt) + align256(szPay)
                      + align256(szCnt) + align256(256) + align256(szOvf); // ~244.3 MB

    if (ws_size >= need) {
        char* ws = (char*)d_ws; size_t off = 0;
        unsigned short* T    = (unsigned short*)(ws + off); off += align256(szT);
        unsigned short* Wt   = (unsigned short*)(ws + off); off += align256(szWt);
        i32x2*          pay  = (i32x2*)         (ws + off); off += align256(szPay);
        int*            cnt  = (int*)           (ws + off); off += align256(szCnt);
        int*            ovfc = (int*)           (ws + off); off += align256(256);
        i32x4*          ovf  = (i32x4*)         (ws + off); off += align256(szOvf);

        hipLaunchKernelGGL(cvt_w_kernel, dim3(NUM_RELS * FEAT * FEAT / 256), dim3(256),
                           0, stream, W, Wt);
        hipMemsetAsync(cnt, 0, szCnt, stream);
        hipMemsetAsync(ovfc, 0, 256, stream);

        hipLaunchKernelGGL(gemm_fill_kernel, dim3(NGEMM + FILL_BLOCKS), dim3(256), 0, stream,
                           h, Wt, T, src, dst, rel, norm, cnt, ovfc, ovf, pay);

        hipLaunchKernelGGL(agg_kernel, dim3(N_NODES / 4), dim3(256), 0, stream,
                           T, pay, cnt, ovfc, ovf, out);
        return;
    }

    // last-resort atomic path
    hipMemsetAsync(d_out, 0, (size_t)out_size * sizeof(float), stream);
    hipLaunchKernelGGL(rgcn_edge_kernel, dim3(16 * 128), dim3(256), 0, stream,
                       h, W, norm, src, dst, rel, out);
    const int n4 = out_size / 4;
    hipLaunchKernelGGL(relu_kernel, dim3((n4 + 255) / 256), dim3(256), 0, stream,
                       (float4*)d_out, n4);
}